// Round 6
// baseline (284.622 us; speedup 1.0000x reference)
//
#include <hip/hip_runtime.h>

#define B_SZ    16
#define T_LEN   1024
#define C_CH    32
#define TC      (T_LEN * C_CH)      // 32768
#define S_MAIN  128
#define NB_P    400
#define P_TOP   60
#define OUT_CH  (NB_P + P_TOP)      // 460

typedef float v4f __attribute__((ext_vector_type(4)));

__device__ __forceinline__ float leaky(float v) {
    return (v > 0.f) ? v : 0.3f * v;
}

// ---------------------------------------------------------------------------
// Kernel 1: transpose x [B, T*C] -> xT [T*C, 16] so one index's 16 batches
// occupy exactly one 64B line.
// ---------------------------------------------------------------------------
__global__ __launch_bounds__(256) void transpose_x(const float* __restrict__ x,
                                                   float* __restrict__ xT) {
    __shared__ float tile[16][129];   // +1 pad breaks bank conflicts
    const int i0 = blockIdx.x * 128;
    const int t  = threadIdx.x;       // 0..255
    #pragma unroll
    for (int r = 0; r < 8; ++r) {
        int e  = r * 256 + t;
        int b  = e >> 7;              // /128
        int ii = e & 127;
        tile[b][ii] = x[b * TC + i0 + ii];
    }
    __syncthreads();
    #pragma unroll
    for (int r = 0; r < 8; ++r) {
        int e  = r * 256 + t;
        int ii = e >> 4;              // /16
        int b  = e & 15;
        xT[i0 * 16 + e] = tile[b][ii];
    }
}

// ---------------------------------------------------------------------------
// Patch compute v6: line-coalesced gathers.
// One wave per pair. lane = jp*16 + b : b = batch (0..15), jp = k-quarter.
// Gather: 16 b-lanes read xT[idx*16 + b] = 16 consecutive floats of ONE
// 64B line -> coalescer merges to 1 transaction per index (4 per instr).
// Per pair: 128 gather transactions (minimum possible) vs 512 in r1.
// Reduction over jp: just 2 shfl_xor steps. Store: coalesced 16-lane burst.
// ---------------------------------------------------------------------------
template <int NPAIR_P, int NROWS, bool TO_WS>
__global__ __launch_bounds__(256) void patch_coal(
    const float* __restrict__ xT,     // [TC][16]
    const int*   __restrict__ idx,    // [NROWS*NPAIR_P, 128]
    const float* __restrict__ W,      // [NROWS*NPAIR_P, 128]
    const float* __restrict__ bias,   // [NROWS*NPAIR_P]
    float*       __restrict__ dst)    // ws [16,NROWS,NPAIR_P] or out [16,T,460]
{
    const int wave = threadIdx.x >> 6;
    const int lane = threadIdx.x & 63;
    const int pair = blockIdx.x * 4 + wave;
    const int b    = lane & 15;       // batch
    const int jp   = lane >> 4;       // k-quarter 0..3

    const int4* i4 = (const int4*)(idx + (size_t)pair * 128 + jp * 32);
    const v4f*  w4 = (const v4f*) (W   + (size_t)pair * 128 + jp * 32);

    float acc0 = 0.f, acc1 = 0.f;
    #pragma unroll
    for (int r = 0; r < 4; ++r) {
        const int4 iva = i4[2 * r];
        const int4 ivb = i4[2 * r + 1];
        const v4f  wva = w4[2 * r];
        const v4f  wvb = w4[2 * r + 1];
        acc0 += xT[(size_t)iva.x * 16 + b] * wva.x;
        acc1 += xT[(size_t)iva.y * 16 + b] * wva.y;
        acc0 += xT[(size_t)iva.z * 16 + b] * wva.z;
        acc1 += xT[(size_t)iva.w * 16 + b] * wva.w;
        acc0 += xT[(size_t)ivb.x * 16 + b] * wvb.x;
        acc1 += xT[(size_t)ivb.y * 16 + b] * wvb.y;
        acc0 += xT[(size_t)ivb.z * 16 + b] * wvb.z;
        acc1 += xT[(size_t)ivb.w * 16 + b] * wvb.w;
    }
    float acc = acc0 + acc1;

    acc += __shfl_xor(acc, 16);
    acc += __shfl_xor(acc, 32);

    if (jp == 0) {                    // 16 lanes, b = 0..15
        const float bv = bias[pair];
        const int row = pair / NPAIR_P;
        const int p   = pair - row * NPAIR_P;
        const float val = leaky(acc + bv);
        if (TO_WS) {
            dst[((size_t)b * NROWS + row) * NPAIR_P + p] = val;
        } else {
            dst[((size_t)b * T_LEN + row) * OUT_CH + NB_P + p] = val;
        }
    }
}

// ---------------------------------------------------------------------------
// Upsample main result x8 along time into the output (coalesced).
// out row = 460 floats = 115 float4; main part = first 100 float4.
// ---------------------------------------------------------------------------
__global__ __launch_bounds__(256) void upsample_main(const float* __restrict__ ws_main,
                                                     float* __restrict__ out) {
    const int o4 = blockIdx.x * 256 + threadIdx.x;   // < B*T*100 = 1,638,400
    const int row = o4 / 100;
    const int col = o4 - row * 100;
    const int b = row >> 10;         // /1024
    const int t = row & 1023;
    const int s = t >> 3;            // /STRETCH
    const v4f v = ((const v4f*)ws_main)[((size_t)b * S_MAIN + s) * 100 + col];
    ((v4f*)out)[(size_t)row * 115 + col] = v;
}

// ---------------------------------------------------------------------------
extern "C" void kernel_launch(void* const* d_in, const int* in_sizes, int n_in,
                              void* d_out, int out_size, void* d_ws, size_t ws_size,
                              hipStream_t stream) {
    const float* x      = (const float*)d_in[0];
    const float* W_main = (const float*)d_in[1];
    const float* b_main = (const float*)d_in[2];
    const float* W_top  = (const float*)d_in[3];
    const float* b_top  = (const float*)d_in[4];
    const int*  idx_main = (const int*)d_in[5];
    const int*  idx_top  = (const int*)d_in[6];
    float* out = (float*)d_out;

    float* xT      = (float*)d_ws;                                 // 2 MB
    float* ws_main = (float*)((char*)d_ws + (size_t)TC * 16 * 4);  // 3.3 MB

    transpose_x<<<TC / 128, 256, 0, stream>>>(x, xT);

    patch_coal<NB_P, S_MAIN, true>
        <<<(S_MAIN * NB_P) / 4, 256, 0, stream>>>(xT, idx_main, W_main, b_main, ws_main);

    patch_coal<P_TOP, T_LEN, false>
        <<<(T_LEN * P_TOP) / 4, 256, 0, stream>>>(xT, idx_top, W_top, b_top, out);

    upsample_main<<<(B_SZ * T_LEN * 100) / 256, 256, 0, stream>>>(ws_main, out);
}